// Round 7
// baseline (604.646 us; speedup 1.0000x reference)
//
#include <hip/hip_runtime.h>
#include <stdint.h>

// ---------------- common helpers ----------------

typedef __attribute__((ext_vector_type(8))) short frag8;   // 8 bf16 (4 VGPRs), MFMA A/B operand
typedef __attribute__((ext_vector_type(4))) float frag4f;  // 4 fp32, MFMA C/D operand

__device__ __forceinline__ uint16_t f2bf(float f) {
  union { float f; uint32_t i; } x; x.f = f;
  uint32_t r = x.i + 0x7fffu + ((x.i >> 16) & 1u);  // round-to-nearest-even
  return (uint16_t)(r >> 16);
}

#define SCHED0() __builtin_amdgcn_sched_barrier(0)

// ---------------- kernel 0: fused fp32 -> bf16 conversion for all 3 inputs ----------------

__global__ __launch_bounds__(256)
void k_cvt3(const float* __restrict__ sx, const float* __restrict__ sq,
            const float* __restrict__ sp, uint16_t* __restrict__ dx,
            uint16_t* __restrict__ dq, uint16_t* __restrict__ dp, int ok)
{
  if (!ok) return;
  const int n0 = 33554432 / 4, n1 = 1572864 / 4, n2 = 524288 / 4;
  int i = blockIdx.x * 256 + threadIdx.x;
  const int stride = gridDim.x * 256;
  for (; i < n0 + n1 + n2; i += stride) {
    const float* s; uint16_t* d; int k;
    if (i < n0)           { s = sx; d = dx; k = i; }
    else if (i < n0 + n1) { s = sq; d = dq; k = i - n0; }
    else                  { s = sp; d = dp; k = i - n0 - n1; }
    float4 v = ((const float4*)s)[k];
    ushort4 o;
    o.x = f2bf(v.x); o.y = f2bf(v.y); o.z = f2bf(v.z); o.w = f2bf(v.w);
    ((ushort4*)d)[k] = o;
  }
}

// ---------------- kernel 1: fused roll + QKV GEMM + windowed attention ----------------
// grid: 512 M-tiles (128 rows = 8 batches) x 16 heads = 8192 blocks, 256 threads.
// T1 XCD swizzle: logical = (bid&7)*1024 + (bid>>3) (bijective) -> each XCD's
// L2 owns a contiguous band of A-tiles (16x head reuse) + all of w_qkv.
// GEMM loop (verified r4/r5): global_load_lds w16, dbuf, counted vmcnt, XOR
// slot swizzle. LDS 50.5 KB -> 3 blocks/CU.
// Attention tail: swapped-operand QK^T (S^T) makes the softmax j-reduction
// lane-local (64 -> 8 shuffles per wave), P stores pack to ds_write_b64, and
// swapped-operand PV (O^T) makes output stores d-contiguous (32 scalar -> 8
// dwordx2 global stores per wave).

struct SmemEpi  { uint16_t q[128][68]; uint16_t k[128][68];    // 17 KB x2
                  uint16_t vT[64][132]; };                      // 16.5 KB
union Smem1 { uint8_t g[2][20480]; SmemEpi e; };                // 51,712 B -> 3 blocks/CU

__global__ __launch_bounds__(256, 3)
void k_qkv_attn(const uint16_t* __restrict__ xb, const uint16_t* __restrict__ wqkvb,
                const float* __restrict__ b_qkv, const float* __restrict__ rel_pos,
                uint16_t* __restrict__ attn16, int ws_ok)
{
  __shared__ Smem1 sm;
  const int bid  = blockIdx.x;
  const int lgc  = ((bid & 7) << 10) | (bid >> 3);  // XCD-contiguous logical id
  const int h    = lgc & 15;
  const int mt   = lgc >> 4;
  const int t    = threadIdx.x;
  const int lane = t & 63;
  const int wv   = t >> 6;
  const int l15  = lane & 15;
  const int quad = lane >> 4;
  const int wr   = wv & 1;
  const int wc   = wv >> 1;

  if (!ws_ok) {  // ws too small: write zero attn slice (diagnostic), touch no ws
    #pragma unroll
    for (int i = 0; i < 32; ++i) {
      const int local = t + 256 * i;           // 0..8191
      const int row = local >> 6, col = local & 63;
      attn16[(mt * 128 + row) * 1024 + h * 64 + col] = 0;
    }
    return;
  }

  // ---- staging map: 20 chunks of 1 KB (64 lanes x 16 B). Chunks 0..7 = A
  // (128 rows x 64 B), chunks 8..19 = B (192 cols x 64 B). Wave wv stages 5
  // chunks. XOR slot swizzle (both-sides): LDS slot s' holds global slot
  // s = s' ^ ((row>>1)&3); source side collapses to slot_g per lane.
  const int slot_g = (lane & 3) ^ ((lane >> 3) & 3);
  const uint16_t* sp[5];
  int ldsoff[5];
  #pragma unroll
  for (int o = 0; o < 5; ++o) {
    const int c = wv * 5 + o;                  // 0..19
    const int rloc = c * 16 + (lane >> 2);     // tile-local row/col index
    if (c < 8) {                               // A: roll(-8 within 16) folded in
      const int g = mt * 128 + rloc;
      const int srow = (g & ~15) | ((g + 8) & 15);
      sp[o] = xb + srow * 512 + slot_g * 8;
    } else {                                   // B: q/k/v thirds of head h
      const int cb = rloc - 128;               // 0..191
      const int gc = (cb < 64) ? (h * 64 + cb)
                   : (cb < 128) ? (1024 + h * 64 + (cb - 64))
                                : (2048 + h * 64 + (cb - 128));
      sp[o] = wqkvb + gc * 512 + slot_g * 8;
    }
    ldsoff[o] = c * 1024;
  }

  frag4f acc[4][6];
  #pragma unroll
  for (int a = 0; a < 4; ++a)
    #pragma unroll
    for (int b = 0; b < 6; ++b) acc[a][b] = (frag4f)0.0f;

  auto STAGE = [&](int buf, int kk) {
    #pragma unroll
    for (int o = 0; o < 5; ++o)
      __builtin_amdgcn_global_load_lds(
          (const __attribute__((address_space(1))) void*)(sp[o] + kk * 32),
          (__attribute__((address_space(3))) void*)(sm.g[buf] + ldsoff[o]),
          16, 0, 0);
  };

  STAGE(0, 0);

  const int xq = quad ^ ((l15 >> 1) & 3);  // swizzled read slot
  for (int kk = 0; kk < 16; ++kk) {
    const int cur = kk & 1;
    if (kk < 15) {
      STAGE(cur ^ 1, kk + 1);              // issue next; stays in flight over MFMA
      SCHED0();
      asm volatile("s_waitcnt vmcnt(5)" ::: "memory");  // cur's 5 loads done
    } else {
      SCHED0();
      asm volatile("s_waitcnt vmcnt(0)" ::: "memory");
    }
    SCHED0();
    __builtin_amdgcn_s_barrier();          // all waves: cur fully staged
    SCHED0();

    const uint8_t* base = sm.g[cur];
    frag8 af[4], bf[6];
    #pragma unroll
    for (int rt = 0; rt < 4; ++rt)
      af[rt] = *(const frag8*)(base + (wr * 64 + rt * 16 + l15) * 64 + xq * 16);
    #pragma unroll
    for (int ct = 0; ct < 6; ++ct)
      bf[ct] = *(const frag8*)(base + 8192 + ((wc * 6 + ct) * 16 + l15) * 64 + xq * 16);
    #pragma unroll
    for (int rt = 0; rt < 4; ++rt)
      #pragma unroll
      for (int ct = 0; ct < 6; ++ct)
        acc[rt][ct] = __builtin_amdgcn_mfma_f32_16x16x32_bf16(af[rt], bf[ct], acc[rt][ct], 0, 0, 0);

    SCHED0();
    asm volatile("s_waitcnt lgkmcnt(0)" ::: "memory");  // this wave's ds_reads done
    SCHED0();
    __builtin_amdgcn_s_barrier();          // all waves done reading cur -> reusable
    SCHED0();
  }

  // ---- epilogue: +bias (fp32), stage Q, K row-major and V transposed ----
  #pragma unroll
  for (int ct = 0; ct < 6; ++ct) {
    const int C = (wc * 6 + ct) * 16 + l15;  // 0..191
    const int gc = (C < 64) ? (h * 64 + C)
                 : (C < 128) ? (1024 + h * 64 + (C - 64))
                             : (2048 + h * 64 + (C - 128));
    const float bias = b_qkv[gc];
    #pragma unroll
    for (int rt = 0; rt < 4; ++rt) {
      #pragma unroll
      for (int r = 0; r < 4; ++r) {
        const int row = wr * 64 + rt * 16 + quad * 4 + r;  // C-layout: row=quad*4+reg, col=l15
        const uint16_t val = f2bf(acc[rt][ct][r] + bias);
        if (C < 64)       sm.e.q[row][C] = val;
        else if (C < 128) sm.e.k[row][C - 64] = val;
        else              sm.e.vT[C - 128][row] = val;
      }
    }
  }
  __syncthreads();

  // ---- attention phase A: read Q/K frags, swapped QK^T -> S^T ----
  // S^T = mfma(A=K, B=Q): per-lane C holds S[i=l15][j=quad*4+r] (col=i from B,
  // row=j from A) -> softmax's j-reduction is 3 in-lane ops + 2 shuffles.
  const float scl = 0.125f;  // 64^-0.5
  frag8 qa0[2], qa1[2], kb0[2], kb1[2];
  frag4f s2[2];
  #pragma unroll
  for (int bbi = 0; bbi < 2; ++bbi) {
    const int bb = wv * 2 + bbi;
    qa0[bbi] = *(const frag8*)&sm.e.q[bb * 16 + l15][quad * 8];
    qa1[bbi] = *(const frag8*)&sm.e.q[bb * 16 + l15][32 + quad * 8];
    kb0[bbi] = *(const frag8*)&sm.e.k[bb * 16 + l15][quad * 8];
    kb1[bbi] = *(const frag8*)&sm.e.k[bb * 16 + l15][32 + quad * 8];
  }
  #pragma unroll
  for (int bbi = 0; bbi < 2; ++bbi) {
    frag4f s = (frag4f)0.0f;
    s = __builtin_amdgcn_mfma_f32_16x16x32_bf16(kb0[bbi], qa0[bbi], s, 0, 0, 0);
    s = __builtin_amdgcn_mfma_f32_16x16x32_bf16(kb1[bbi], qa1[bbi], s, 0, 0, 0);
    s2[bbi] = s;
  }
  __syncthreads();  // all q reads complete; q storage now reusable for p

  // ---- softmax (mask + rel-pos bias); P stored [i][j] so PV reads b128 ----
  uint16_t (*pp)[16][20] = (uint16_t (*)[16][20])sm.e.q;  // 8x16x20x2B = 5.1 KB, aliases q
  #pragma unroll
  for (int bbi = 0; bbi < 2; ++bbi) {
    const int bb = wv * 2 + bbi;
    const int i = l15;                     // query row (uniform per lane)
    float v[4];
    #pragma unroll
    for (int r = 0; r < 4; ++r) {
      const int j = quad * 4 + r;          // key col
      const int r0 = (i >> 2) - (j >> 2) + 3;
      const int r1 = (i & 3) - (j & 3) + 3;
      const float bias = rel_pos[h * 49 + r0 * 7 + r1];
      const bool msk = ((h >= 14) && (((i >> 2) < 2) != ((j >> 2) < 2))) ||
                       ((h & 1)  && (((i & 3) < 2) != ((j & 3) < 2)));
      v[r] = msk ? -1e30f : (s2[bbi][r] * scl + bias);
    }
    float m = fmaxf(fmaxf(v[0], v[1]), fmaxf(v[2], v[3]));
    m = fmaxf(m, __shfl_xor(m, 16));
    m = fmaxf(m, __shfl_xor(m, 32));
    float e0 = __expf(v[0] - m), e1 = __expf(v[1] - m);
    float e2 = __expf(v[2] - m), e3 = __expf(v[3] - m);
    float su = (e0 + e1) + (e2 + e3);
    su += __shfl_xor(su, 16);
    su += __shfl_xor(su, 32);
    const float rs = 1.0f / su;
    ushort4 pk;
    pk.x = f2bf(e0 * rs); pk.y = f2bf(e1 * rs);
    pk.z = f2bf(e2 * rs); pk.w = f2bf(e3 * rs);
    *(ushort4*)&pp[bb][i][quad * 4] = pk;  // ds_write_b64, j-contiguous
  }
  __syncthreads();

  // ---- O^T = V^T x P^T (swapped PV): same LDS reads as before, but output
  // is d-contiguous per lane -> global_store_dwordx2. K=32 MFMA; j>=16 half
  // zeroed on the B (P) side; A garbage there is finite (x0 = 0).
  #pragma unroll
  for (int bbi = 0; bbi < 2; ++bbi) {
    const int bb = wv * 2 + bbi;
    frag8 pb;
    if (quad < 2) pb = *(const frag8*)&pp[bb][l15][quad * 8];
    else          pb = (frag8)0;
    #pragma unroll
    for (int dt = 0; dt < 4; ++dt) {
      frag8 av = *(const frag8*)&sm.e.vT[dt * 16 + l15][bb * 16 + (quad & 1) * 8];
      frag4f o = (frag4f)0.0f;
      o = __builtin_amdgcn_mfma_f32_16x16x32_bf16(av, pb, o, 0, 0, 0);
      // o[r]: token i = l15 (col), d = dt*16 + quad*4 + r (row)
      ushort4 ok4;
      ok4.x = f2bf(o[0]); ok4.y = f2bf(o[1]);
      ok4.z = f2bf(o[2]); ok4.w = f2bf(o[3]);
      const int grow = mt * 128 + bb * 16 + l15;
      *(ushort4*)&attn16[grow * 1024 + h * 64 + dt * 16 + quad * 4] = ok4;
    }
  }
}

// ---------------- kernel 2: projection GEMM (M=65536, K=1024, N=512) + bias, fp32 out ----------------
// In-place constraint: out fp32 row r occupies the same 2048 bytes as attn16 bf16
// row r, so a block must own COMPLETE rows (read all K before writing any col).
// grid 1024 blocks x 512 threads, tile 64 x 512, BK=32, global_load_lds dbuf,
// ONE __syncthreads per K-step, XOR slot swizzle. (r3 structure; r4 asm variant
// was equivalent within noise.)

__global__ __launch_bounds__(512, 4)
void k_proj(const uint16_t* __restrict__ attn16, const uint16_t* __restrict__ wprojb,
            const float* __restrict__ b_proj, float* __restrict__ out, int ws_ok)
{
  __shared__ uint8_t smraw[2 * 36864];  // 2 x (A 4096 B + B 32768 B) = 72 KB
  const int mt   = blockIdx.x;          // 0..1023, rows [mt*64, mt*64+64)
  const int t    = threadIdx.x;
  const int lane = t & 63;
  const int wv   = t >> 6;              // 0..7
  const int l15  = lane & 15;
  const int quad = lane >> 4;

  if (!ws_ok) {  // diagnostic fallback: bias only
    for (int i = t; i < 64 * 512; i += 512) {
      const int row = i >> 9, col = i & 511;
      out[(mt * 64 + row) * 512 + col] = b_proj[col];
    }
    return;
  }

  // ---- staging map: 36 chunks of 1 KB. Chunks 0..3 = A (64 rows x 64 B),
  // chunks 4..35 = B (512 cols x 64 B). XOR slot swizzle on the source side.
  const int cnt = (wv < 4) ? 5 : 4;
  const int c0  = (wv < 4) ? wv * 5 : 20 + (wv - 4) * 4;
  const int slot_g = (lane & 3) ^ ((lane >> 3) & 3);

  const uint16_t* gp[5];
  int lds_off[5];
  #pragma unroll
  for (int o = 0; o < 5; ++o) {
    int c = c0 + o;
    if (c > 35) c = 35;                          // clamp unused slot (never issued)
    const int rloc = c * 16 + (lane >> 2);       // tile-local row/col
    if (c < 4) {                                 // A region: rows 0..63
      gp[o] = attn16 + (size_t)(mt * 64 + rloc) * 1024 + slot_g * 8;
    } else {                                     // B region: cols 0..511
      gp[o] = wprojb + (size_t)(rloc - 64) * 1024 + slot_g * 8;
    }
    lds_off[o] = (c0 + o) * 1024;
  }

  frag4f acc[4][4];
  #pragma unroll
  for (int a = 0; a < 4; ++a)
    #pragma unroll
    for (int b = 0; b < 4; ++b) acc[a][b] = (frag4f)0.0f;

  auto STAGE = [&](int buf, int kk) {
    #pragma unroll
    for (int o = 0; o < 5; ++o)
      if (o < cnt)
        __builtin_amdgcn_global_load_lds(
            (const __attribute__((address_space(1))) void*)(gp[o] + kk * 32),
            (__attribute__((address_space(3))) void*)(smraw + buf * 36864 + lds_off[o]),
            16, 0, 0);
  };

  STAGE(0, 0);
  __syncthreads();  // drains vmcnt(0): buf0 ready

  const int xq = quad ^ ((l15 >> 1) & 3);  // swizzled read slot
  for (int kk = 0; kk < 32; ++kk) {
    const int cur = kk & 1;
    if (kk < 31) STAGE(cur ^ 1, kk + 1);  // issue next tile; flies under compute

    const uint16_t* As = (const uint16_t*)(smraw + cur * 36864);
    const uint16_t* Bs = (const uint16_t*)(smraw + cur * 36864 + 4096);
    frag8 af[4];
    #pragma unroll
    for (int rt = 0; rt < 4; ++rt)
      af[rt] = *(const frag8*)(As + (rt * 16 + l15) * 32 + xq * 8);
    #pragma unroll
    for (int ct = 0; ct < 4; ++ct) {
      frag8 bfr = *(const frag8*)(Bs + (wv * 64 + ct * 16 + l15) * 32 + xq * 8);
      #pragma unroll
      for (int rt = 0; rt < 4; ++rt)
        acc[rt][ct] = __builtin_amdgcn_mfma_f32_16x16x32_bf16(af[rt], bfr, acc[rt][ct], 0, 0, 0);
    }
    __syncthreads();  // vmcnt(0)+lgkm drain: next buf ready; all waves done reading cur
  }

  // ---- epilogue: + bias, fp32 stores (after final barrier -> all A reads done)
  #pragma unroll
  for (int ct = 0; ct < 4; ++ct) {
    const int gcol = wv * 64 + ct * 16 + l15;
    const float bias = b_proj[gcol];
    #pragma unroll
    for (int rt = 0; rt < 4; ++rt) {
      #pragma unroll
      for (int r = 0; r < 4; ++r) {
        const int grow = mt * 64 + rt * 16 + quad * 4 + r;  // C-layout: row=quad*4+reg
        out[grow * 512 + gcol] = acc[rt][ct][r] + bias;
      }
    }
  }
}

// ---------------- launch ----------------

extern "C" void kernel_launch(void* const* d_in, const int* in_sizes, int n_in,
                              void* d_out, int out_size, void* d_ws, size_t ws_size,
                              hipStream_t stream) {
  const float* x      = (const float*)d_in[0];   // (4096,16,512) fp32
  const float* w_qkv  = (const float*)d_in[1];   // (3072,512)    fp32
  const float* b_qkv  = (const float*)d_in[2];   // (3072,)       fp32
  const float* w_proj = (const float*)d_in[3];   // (512,1024)    fp32
  const float* b_proj = (const float*)d_in[4];   // (512,)        fp32
  const float* rel    = (const float*)d_in[5];   // (16,7,7)      fp32

  // ws layout (bf16): x 33,554,432 | w_qkv 1,572,864 | w_proj 524,288 el
  uint16_t* xb     = (uint16_t*)d_ws;
  uint16_t* wqkvb  = xb + 33554432;
  uint16_t* wprojb = wqkvb + 1572864;
  const size_t ws_need = (size_t)(33554432 + 1572864 + 524288) * 2;
  const int ws_ok = (ws_size >= ws_need) ? 1 : 0;

  // d_out bytes: phase 1 = bf16 attn (65536 x 1024 x 2B), phase 2 = fp32 out (65536 x 512 x 4B)
  uint16_t* attn16 = (uint16_t*)d_out;
  float*    out    = (float*)d_out;

  k_cvt3<<<dim3(2048), dim3(256), 0, stream>>>(x, w_qkv, w_proj, xb, wqkvb, wprojb, ws_ok);
  k_qkv_attn<<<dim3(512 * 16), dim3(256), 0, stream>>>(xb, wqkvb, b_qkv, rel, attn16, ws_ok);
  k_proj    <<<dim3(1024),     dim3(512), 0, stream>>>(attn16, wprojb, b_proj, out, ws_ok);
}

// Round 8
// 598.587 us; speedup vs baseline: 1.0101x; 1.0101x over previous
//
#include <hip/hip_runtime.h>
#include <stdint.h>

// ---------------- common helpers ----------------

typedef __attribute__((ext_vector_type(8))) short frag8;   // 8 bf16 (4 VGPRs), MFMA A/B operand
typedef __attribute__((ext_vector_type(4))) float frag4f;  // 4 fp32, MFMA C/D operand

__device__ __forceinline__ uint16_t f2bf(float f) {
  union { float f; uint32_t i; } x; x.f = f;
  uint32_t r = x.i + 0x7fffu + ((x.i >> 16) & 1u);  // round-to-nearest-even
  return (uint16_t)(r >> 16);
}

#define SCHED0() __builtin_amdgcn_sched_barrier(0)

// ---------------- kernel 0: fp32 -> bf16 conversion, block-range partitioned ----------------
// blocks 0..2047 -> x (4096 f4 each), 2048..2239 -> w_qkv (2048 f4), 2240..2303 -> w_proj.

__global__ __launch_bounds__(256)
void k_cvt3(const float* __restrict__ sx, const float* __restrict__ sq,
            const float* __restrict__ sp, uint16_t* __restrict__ dx,
            uint16_t* __restrict__ dq, uint16_t* __restrict__ dp, int ok)
{
  if (!ok) return;
  const int b = blockIdx.x;
  const float* s; uint16_t* d; int base, n;
  if (b < 2048)      { s = sx; d = dx; base = b * 4096;          n = 4096; }
  else if (b < 2240) { s = sq; d = dq; base = (b - 2048) * 2048; n = 2048; }
  else               { s = sp; d = dp; base = (b - 2240) * 2048; n = 2048; }
  for (int i = threadIdx.x; i < n; i += 256) {
    float4 v = ((const float4*)s)[base + i];
    ushort4 o;
    o.x = f2bf(v.x); o.y = f2bf(v.y); o.z = f2bf(v.z); o.w = f2bf(v.w);
    ((ushort4*)d)[base + i] = o;
  }
}

// ---------------- kernel 1: fused roll + QKV GEMM + windowed attention ----------------
// grid: 512 M-tiles (128 rows = 8 batches) x 16 heads = 8192 blocks, 256 threads.
// T1 XCD swizzle: logical = (bid&7)*1024 + (bid>>3) (bijective) -> each XCD's
// L2 owns a contiguous band of A-tiles (16x head reuse) + all of w_qkv.
// GEMM loop: global_load_lds w16, dbuf, counted vmcnt, XOR slot swizzle,
// + T5 setprio(1) around the MFMA cluster (multi-block co-residency gives the
// CU scheduler wave-role diversity). LDS 50.5 KB -> 3 blocks/CU.
// Attention tail: swapped-operand QK^T / PV (lane-local softmax, packed stores).

struct SmemEpi  { uint16_t q[128][68]; uint16_t k[128][68];    // 17 KB x2
                  uint16_t vT[64][132]; };                      // 16.5 KB
union Smem1 { uint8_t g[2][20480]; SmemEpi e; };                // 51,712 B -> 3 blocks/CU

__global__ __launch_bounds__(256, 3)
void k_qkv_attn(const uint16_t* __restrict__ xb, const uint16_t* __restrict__ wqkvb,
                const float* __restrict__ b_qkv, const float* __restrict__ rel_pos,
                uint16_t* __restrict__ attn16, int ws_ok)
{
  __shared__ Smem1 sm;
  const int bid  = blockIdx.x;
  const int lgc  = ((bid & 7) << 10) | (bid >> 3);  // XCD-contiguous logical id
  const int h    = lgc & 15;
  const int mt   = lgc >> 4;
  const int t    = threadIdx.x;
  const int lane = t & 63;
  const int wv   = t >> 6;
  const int l15  = lane & 15;
  const int quad = lane >> 4;
  const int wr   = wv & 1;
  const int wc   = wv >> 1;

  if (!ws_ok) {  // ws too small: write zero attn slice (diagnostic), touch no ws
    #pragma unroll
    for (int i = 0; i < 32; ++i) {
      const int local = t + 256 * i;           // 0..8191
      const int row = local >> 6, col = local & 63;
      attn16[(mt * 128 + row) * 1024 + h * 64 + col] = 0;
    }
    return;
  }

  // ---- staging map: 20 chunks of 1 KB (64 lanes x 16 B). Chunks 0..7 = A
  // (128 rows x 64 B), chunks 8..19 = B (192 cols x 64 B). Wave wv stages 5
  // chunks. XOR slot swizzle (both-sides): LDS slot s' holds global slot
  // s = s' ^ ((row>>1)&3); source side collapses to slot_g per lane.
  const int slot_g = (lane & 3) ^ ((lane >> 3) & 3);
  const uint16_t* sp[5];
  int ldsoff[5];
  #pragma unroll
  for (int o = 0; o < 5; ++o) {
    const int c = wv * 5 + o;                  // 0..19
    const int rloc = c * 16 + (lane >> 2);     // tile-local row/col index
    if (c < 8) {                               // A: roll(-8 within 16) folded in
      const int g = mt * 128 + rloc;
      const int srow = (g & ~15) | ((g + 8) & 15);
      sp[o] = xb + srow * 512 + slot_g * 8;
    } else {                                   // B: q/k/v thirds of head h
      const int cb = rloc - 128;               // 0..191
      const int gc = (cb < 64) ? (h * 64 + cb)
                   : (cb < 128) ? (1024 + h * 64 + (cb - 64))
                                : (2048 + h * 64 + (cb - 128));
      sp[o] = wqkvb + gc * 512 + slot_g * 8;
    }
    ldsoff[o] = c * 1024;
  }

  frag4f acc[4][6];
  #pragma unroll
  for (int a = 0; a < 4; ++a)
    #pragma unroll
    for (int b = 0; b < 6; ++b) acc[a][b] = (frag4f)0.0f;

  auto STAGE = [&](int buf, int kk) {
    #pragma unroll
    for (int o = 0; o < 5; ++o)
      __builtin_amdgcn_global_load_lds(
          (const __attribute__((address_space(1))) void*)(sp[o] + kk * 32),
          (__attribute__((address_space(3))) void*)(sm.g[buf] + ldsoff[o]),
          16, 0, 0);
  };

  STAGE(0, 0);

  const int xq = quad ^ ((l15 >> 1) & 3);  // swizzled read slot
  for (int kk = 0; kk < 16; ++kk) {
    const int cur = kk & 1;
    if (kk < 15) {
      STAGE(cur ^ 1, kk + 1);              // issue next; stays in flight over MFMA
      SCHED0();
      asm volatile("s_waitcnt vmcnt(5)" ::: "memory");  // cur's 5 loads done
    } else {
      SCHED0();
      asm volatile("s_waitcnt vmcnt(0)" ::: "memory");
    }
    SCHED0();
    __builtin_amdgcn_s_barrier();          // all waves: cur fully staged
    SCHED0();

    const uint8_t* base = sm.g[cur];
    frag8 af[4], bf[6];
    #pragma unroll
    for (int rt = 0; rt < 4; ++rt)
      af[rt] = *(const frag8*)(base + (wr * 64 + rt * 16 + l15) * 64 + xq * 16);
    #pragma unroll
    for (int ct = 0; ct < 6; ++ct)
      bf[ct] = *(const frag8*)(base + 8192 + ((wc * 6 + ct) * 16 + l15) * 64 + xq * 16);
    __builtin_amdgcn_s_setprio(1);
    #pragma unroll
    for (int rt = 0; rt < 4; ++rt)
      #pragma unroll
      for (int ct = 0; ct < 6; ++ct)
        acc[rt][ct] = __builtin_amdgcn_mfma_f32_16x16x32_bf16(af[rt], bf[ct], acc[rt][ct], 0, 0, 0);
    __builtin_amdgcn_s_setprio(0);

    SCHED0();
    asm volatile("s_waitcnt lgkmcnt(0)" ::: "memory");  // this wave's ds_reads done
    SCHED0();
    __builtin_amdgcn_s_barrier();          // all waves done reading cur -> reusable
    SCHED0();
  }

  // ---- epilogue: +bias (fp32), stage Q, K row-major and V transposed ----
  #pragma unroll
  for (int ct = 0; ct < 6; ++ct) {
    const int C = (wc * 6 + ct) * 16 + l15;  // 0..191
    const int gc = (C < 64) ? (h * 64 + C)
                 : (C < 128) ? (1024 + h * 64 + (C - 64))
                             : (2048 + h * 64 + (C - 128));
    const float bias = b_qkv[gc];
    #pragma unroll
    for (int rt = 0; rt < 4; ++rt) {
      #pragma unroll
      for (int r = 0; r < 4; ++r) {
        const int row = wr * 64 + rt * 16 + quad * 4 + r;  // C-layout: row=quad*4+reg, col=l15
        const uint16_t val = f2bf(acc[rt][ct][r] + bias);
        if (C < 64)       sm.e.q[row][C] = val;
        else if (C < 128) sm.e.k[row][C - 64] = val;
        else              sm.e.vT[C - 128][row] = val;
      }
    }
  }
  __syncthreads();

  // ---- attention phase A: read Q/K frags, swapped QK^T -> S^T ----
  // S^T = mfma(A=K, B=Q): per-lane C holds S[i=l15][j=quad*4+r].
  const float scl = 0.125f;  // 64^-0.5
  frag8 qa0[2], qa1[2], kb0[2], kb1[2];
  frag4f s2[2];
  #pragma unroll
  for (int bbi = 0; bbi < 2; ++bbi) {
    const int bb = wv * 2 + bbi;
    qa0[bbi] = *(const frag8*)&sm.e.q[bb * 16 + l15][quad * 8];
    qa1[bbi] = *(const frag8*)&sm.e.q[bb * 16 + l15][32 + quad * 8];
    kb0[bbi] = *(const frag8*)&sm.e.k[bb * 16 + l15][quad * 8];
    kb1[bbi] = *(const frag8*)&sm.e.k[bb * 16 + l15][32 + quad * 8];
  }
  #pragma unroll
  for (int bbi = 0; bbi < 2; ++bbi) {
    frag4f s = (frag4f)0.0f;
    s = __builtin_amdgcn_mfma_f32_16x16x32_bf16(kb0[bbi], qa0[bbi], s, 0, 0, 0);
    s = __builtin_amdgcn_mfma_f32_16x16x32_bf16(kb1[bbi], qa1[bbi], s, 0, 0, 0);
    s2[bbi] = s;
  }
  __syncthreads();  // all q reads complete; q storage now reusable for p

  // ---- softmax (mask + rel-pos bias); P stored [i][j] so PV reads b128 ----
  uint16_t (*pp)[16][20] = (uint16_t (*)[16][20])sm.e.q;  // 8x16x20x2B = 5.1 KB, aliases q
  #pragma unroll
  for (int bbi = 0; bbi < 2; ++bbi) {
    const int bb = wv * 2 + bbi;
    const int i = l15;                     // query row (uniform per lane)
    float v[4];
    #pragma unroll
    for (int r = 0; r < 4; ++r) {
      const int j = quad * 4 + r;          // key col
      const int r0 = (i >> 2) - (j >> 2) + 3;
      const int r1 = (i & 3) - (j & 3) + 3;
      const float bias = rel_pos[h * 49 + r0 * 7 + r1];
      const bool msk = ((h >= 14) && (((i >> 2) < 2) != ((j >> 2) < 2))) ||
                       ((h & 1)  && (((i & 3) < 2) != ((j & 3) < 2)));
      v[r] = msk ? -1e30f : (s2[bbi][r] * scl + bias);
    }
    float m = fmaxf(fmaxf(v[0], v[1]), fmaxf(v[2], v[3]));
    m = fmaxf(m, __shfl_xor(m, 16));
    m = fmaxf(m, __shfl_xor(m, 32));
    float e0 = __expf(v[0] - m), e1 = __expf(v[1] - m);
    float e2 = __expf(v[2] - m), e3 = __expf(v[3] - m);
    float su = (e0 + e1) + (e2 + e3);
    su += __shfl_xor(su, 16);
    su += __shfl_xor(su, 32);
    const float rs = 1.0f / su;
    ushort4 pk;
    pk.x = f2bf(e0 * rs); pk.y = f2bf(e1 * rs);
    pk.z = f2bf(e2 * rs); pk.w = f2bf(e3 * rs);
    *(ushort4*)&pp[bb][i][quad * 4] = pk;  // ds_write_b64, j-contiguous
  }
  __syncthreads();

  // ---- O^T = V^T x P^T (swapped PV): output d-contiguous per lane ----
  #pragma unroll
  for (int bbi = 0; bbi < 2; ++bbi) {
    const int bb = wv * 2 + bbi;
    frag8 pb;
    if (quad < 2) pb = *(const frag8*)&pp[bb][l15][quad * 8];
    else          pb = (frag8)0;
    #pragma unroll
    for (int dt = 0; dt < 4; ++dt) {
      frag8 av = *(const frag8*)&sm.e.vT[dt * 16 + l15][bb * 16 + (quad & 1) * 8];
      frag4f o = (frag4f)0.0f;
      o = __builtin_amdgcn_mfma_f32_16x16x32_bf16(av, pb, o, 0, 0, 0);
      // o[r]: token i = l15 (col), d = dt*16 + quad*4 + r (row)
      ushort4 ok4;
      ok4.x = f2bf(o[0]); ok4.y = f2bf(o[1]);
      ok4.z = f2bf(o[2]); ok4.w = f2bf(o[3]);
      const int grow = mt * 128 + bb * 16 + l15;
      *(ushort4*)&attn16[grow * 1024 + h * 64 + dt * 16 + quad * 4] = ok4;
    }
  }
}

// ---------------- kernel 2: projection GEMM (M=65536, K=1024, N=512) + bias, fp32 out ----------------
// In-place constraint: out fp32 row r overlays attn16 bf16 row r -> block owns
// COMPLETE rows, all K read before any store.
// NEW (r8): BM=128 -> 512 blocks x 1024 threads (16 waves, grid 2x8, wave tile
// 64x64, acc=64 VGPR). Halves B-panel traffic per row (L2/CU-step 72->40 KB).
// At 1 block/CU there is no co-resident block to hide the staging drain, so:
// TRIPLE-buffered LDS (3 x 40 KB = 120 KB) + counted vmcnt, 2-step prefetch
// depth (covers ~900-cyc HBM latency under ~2 compute phases).

__global__ __launch_bounds__(1024, 4)
void k_proj(const uint16_t* __restrict__ attn16, const uint16_t* __restrict__ wprojb,
            const float* __restrict__ b_proj, float* __restrict__ out, int ws_ok)
{
  __shared__ uint8_t smraw[3 * 40960];  // 3 x (A 8192 B + B 32768 B) = 120 KB
  const int mt   = blockIdx.x;          // 0..511, rows [mt*128, mt*128+128)
  const int t    = threadIdx.x;
  const int lane = t & 63;
  const int wv   = t >> 6;              // 0..15
  const int l15  = lane & 15;
  const int quad = lane >> 4;
  const int wr2  = wv & 1;              // row half (64 rows)
  const int wc8  = wv >> 1;             // col group (64 cols)

  if (!ws_ok) {  // diagnostic fallback: bias only
    for (int i = t; i < 128 * 512; i += 1024) {
      const int row = i >> 9, col = i & 511;
      out[(mt * 128 + row) * 512 + col] = b_proj[col];
    }
    return;
  }

  // ---- staging map: 40 chunks of 1 KB (64 lanes x 16 B). Chunks 0..7 = A
  // (128 rows x 64 B), chunks 8..39 = B (512 cols x 64 B). Waves 0..7 stage 3
  // chunks, waves 8..15 stage 2 (8*3+8*2=40). XOR slot swizzle on the source.
  const int cnt = (wv < 8) ? 3 : 2;
  const int c0  = (wv < 8) ? wv * 3 : 24 + (wv - 8) * 2;
  const int slot_g = (lane & 3) ^ ((lane >> 3) & 3);

  const uint16_t* gp[3];
  int lds_off[3];
  #pragma unroll
  for (int o = 0; o < 3; ++o) {
    int c = c0 + o;
    if (c > 39) c = 39;                          // clamp unused slot (never issued)
    const int rloc = c * 16 + (lane >> 2);       // tile-local row/col
    if (c < 8) {                                 // A region: rows 0..127
      gp[o] = attn16 + (size_t)(mt * 128 + rloc) * 1024 + slot_g * 8;
    } else {                                     // B region: cols 0..511
      gp[o] = wprojb + (size_t)(rloc - 128) * 1024 + slot_g * 8;
    }
    lds_off[o] = (c0 + o) * 1024;
  }

  frag4f acc[4][4];
  #pragma unroll
  for (int a = 0; a < 4; ++a)
    #pragma unroll
    for (int b = 0; b < 4; ++b) acc[a][b] = (frag4f)0.0f;

  auto STAGE = [&](int buf, int kk) {
    #pragma unroll
    for (int o = 0; o < 3; ++o)
      if (o < cnt)
        __builtin_amdgcn_global_load_lds(
            (const __attribute__((address_space(1))) void*)(gp[o] + kk * 32),
            (__attribute__((address_space(3))) void*)(smraw + buf * 40960 + lds_off[o]),
            16, 0, 0);
  };

  STAGE(0, 0);
  STAGE(1, 1);

  const int xq = quad ^ ((l15 >> 1) & 3);  // swizzled read slot
  int cur = 0;
  for (int kk = 0; kk < 32; ++kk) {
    if (kk < 30) {
      int nb = cur + 2; if (nb >= 3) nb -= 3;
      STAGE(nb, kk + 2);                   // 2-deep prefetch
      SCHED0();
      if (wv < 8) asm volatile("s_waitcnt vmcnt(6)" ::: "memory");  // kk's loads done
      else        asm volatile("s_waitcnt vmcnt(4)" ::: "memory");
    } else if (kk == 30) {
      SCHED0();
      if (wv < 8) asm volatile("s_waitcnt vmcnt(3)" ::: "memory");
      else        asm volatile("s_waitcnt vmcnt(2)" ::: "memory");
    } else {
      SCHED0();
      asm volatile("s_waitcnt vmcnt(0)" ::: "memory");
    }
    SCHED0();
    __builtin_amdgcn_s_barrier();          // all waves: kk fully staged
    SCHED0();

    const uint16_t* As = (const uint16_t*)(smraw + cur * 40960);
    const uint16_t* Bs = (const uint16_t*)(smraw + cur * 40960 + 8192);
    frag8 af[4];
    #pragma unroll
    for (int rt = 0; rt < 4; ++rt)
      af[rt] = *(const frag8*)(As + (wr2 * 64 + rt * 16 + l15) * 32 + xq * 8);
    #pragma unroll
    for (int ct = 0; ct < 4; ++ct) {
      frag8 bfr = *(const frag8*)(Bs + (wc8 * 64 + ct * 16 + l15) * 32 + xq * 8);
      #pragma unroll
      for (int rt = 0; rt < 4; ++rt)
        acc[rt][ct] = __builtin_amdgcn_mfma_f32_16x16x32_bf16(af[rt], bfr, acc[rt][ct], 0, 0, 0);
    }

    SCHED0();
    asm volatile("s_waitcnt lgkmcnt(0)" ::: "memory");  // this wave's ds_reads done
    SCHED0();
    __builtin_amdgcn_s_barrier();          // all waves done reading kk -> buf reusable
    SCHED0();
    ++cur; if (cur >= 3) cur -= 3;
  }

  // ---- epilogue: + bias, fp32 stores (after final barrier -> all A reads done)
  #pragma unroll
  for (int ct = 0; ct < 4; ++ct) {
    const int gcol = wc8 * 64 + ct * 16 + l15;
    const float bias = b_proj[gcol];
    #pragma unroll
    for (int rt = 0; rt < 4; ++rt) {
      #pragma unroll
      for (int r = 0; r < 4; ++r) {
        const int grow = mt * 128 + wr2 * 64 + rt * 16 + quad * 4 + r;
        out[grow * 512 + gcol] = acc[rt][ct][r] + bias;
      }
    }
  }
}

// ---------------- launch ----------------

extern "C" void kernel_launch(void* const* d_in, const int* in_sizes, int n_in,
                              void* d_out, int out_size, void* d_ws, size_t ws_size,
                              hipStream_t stream) {
  const float* x      = (const float*)d_in[0];   // (4096,16,512) fp32
  const float* w_qkv  = (const float*)d_in[1];   // (3072,512)    fp32
  const float* b_qkv  = (const float*)d_in[2];   // (3072,)       fp32
  const float* w_proj = (const float*)d_in[3];   // (512,1024)    fp32
  const float* b_proj = (const float*)d_in[4];   // (512,)        fp32
  const float* rel    = (const float*)d_in[5];   // (16,7,7)      fp32

  // ws layout (bf16): x 33,554,432 | w_qkv 1,572,864 | w_proj 524,288 el
  uint16_t* xb     = (uint16_t*)d_ws;
  uint16_t* wqkvb  = xb + 33554432;
  uint16_t* wprojb = wqkvb + 1572864;
  const size_t ws_need = (size_t)(33554432 + 1572864 + 524288) * 2;
  const int ws_ok = (ws_size >= ws_need) ? 1 : 0;

  // d_out bytes: phase 1 = bf16 attn (65536 x 1024 x 2B), phase 2 = fp32 out (65536 x 512 x 4B)
  uint16_t* attn16 = (uint16_t*)d_out;
  float*    out    = (float*)d_out;

  k_cvt3<<<dim3(2304), dim3(256), 0, stream>>>(x, w_qkv, w_proj, xb, wqkvb, wprojb, ws_ok);
  k_qkv_attn<<<dim3(512 * 16), dim3(256), 0, stream>>>(xb, wqkvb, b_qkv, rel, attn16, ws_ok);
  k_proj    <<<dim3(512),      dim3(1024), 0, stream>>>(attn16, wprojb, b_proj, out, ws_ok);
}